// Round 14
// baseline (697.747 us; speedup 1.0000x reference)
//
#include <hip/hip_runtime.h>

// Greedy NMS: keep[i] = !any(keep[j] for j in knn[i] if j < i)
//
// Round-14 = Round-12 wait/publish structure (best: 549us chain) with the
// on-turn fixed-point replaced by a PRECOMPUTED-LEVELS resolve:
//   - R13 falsified on-turn probe/mirror shaves; linear-in-CHUNK per-step
//     (R9/R10) fingers the iterate-until-converge fixed-point (~5.5us of the
//     7.5us step) as the real cost.
//   - topo levels of the intra-chunk DAG + level-ordered worklist are computed
//     OFF-TURN during the wait (structure is known at classification; only
//     init values arrive at the turn).
//   - on-turn: one probe pass per level (preds final), st = anyKept?2:1,
//     plain barrier per level. No convergence checks. Overflow-tainted rows
//     (P~1e-7) -> rare global-rescan catch-all loop.
//
// Output encoding (validated round 4): INT32.
//   d_out[0..M)        : kept flags, 1 / 0
//   d_out[M..M+M*64)   : kept_knn, idx or 150000 (tail doubles as bitmask
//                        scratch, owned by block 73 which never publishes)
// d_ws[0..3]: progress counter (zeroed by init kernel each call)

#define M_ROWS 150000
#define KNN    64
#define BLK    1024
#define QRT    2
#define CHUNK  (BLK * QRT)                        // 2048
#define NCH    ((M_ROWS + CHUNK - 1) / CHUNK)     // 74
#define ICAP   6
#define ECAP   12
#define WCH    4                                  // exl window, chunks
#define NLVL   32                                 // level buckets (>=NLVL-1 -> catch-all)
#define LMW    (((NCH - 1) * CHUNK) / 32)         // 4672 u32 bitmask words
#define OUT_INTS (M_ROWS + M_ROWS * KNN)
#define BMG_OFF  (OUT_INTS - LMW)
#define SPINMAX  (1 << 22)

__global__ void init_ws_kernel(unsigned int* progress) {
  if (threadIdx.x == 0) *progress = 0u;
}

__device__ __forceinline__ unsigned int bm_load(const unsigned int* p) {
  return __hip_atomic_load(p, __ATOMIC_RELAXED, __HIP_MEMORY_SCOPE_AGENT);
}

// reload a row and probe preds j in [lo, hi) against the LDS bitmask
__device__ __forceinline__ bool probe_reload(const int* __restrict__ rp,
                                             const unsigned int* lm,
                                             int lo, int hi) {
  bool s = false;
#pragma unroll
  for (int u = 0; u < 16; ++u) {
    int4 d = ((const int4*)rp)[u];
    int js[4] = {d.x, d.y, d.z, d.w};
#pragma unroll
    for (int m = 0; m < 4; ++m) {
      int j = js[m];
      if (j >= lo && j < hi && ((lm[j >> 5] >> (j & 31)) & 1u)) s = true;
    }
  }
  return s;
}

__global__ __launch_bounds__(BLK) void nms_chain_kernel(
    const int* __restrict__ knn,
    int* __restrict__ out,
    unsigned int* __restrict__ progress)
{
  const int b    = blockIdx.x;
  const int t    = threadIdx.x;
  const int base = b * CHUNK;
  const int winb = (b > WCH) ? (base - WCH * CHUNK) : 0;   // exl window base

  unsigned int* bmg = (unsigned int*)out + BMG_OFF;
  unsigned long long* bmg64 = (unsigned long long*)bmg;

  __shared__ unsigned char      st[CHUNK];        // 0 unk, 1 kept, 2 supp
  __shared__ unsigned char      lvl[CHUNK];       // 0..31, 254 catch-all, 255 unknown
  __shared__ unsigned char      icn[CHUNK];       // intra pred count (non-ovf)
  __shared__ unsigned short     il[ICAP][CHUNK];  // transposed intra lists
  __shared__ unsigned short     exl[ECAP][CHUNK]; // transposed window lists
  __shared__ unsigned short     wl[CHUNK];        // level-ordered worklist
  __shared__ unsigned int       lm[LMW];          // mirrored keep bits
  __shared__ unsigned int       lvlcnt[NLVL], lvloff[NLVL], lvlpos[NLVL];
  __shared__ unsigned long long bw[QRT][BLK / 64];
  __shared__ unsigned int       sh_p;
  __shared__ int                sh_lmax, any254;

  int  rowq[QRT];
  bool vq[QRT], ovf[QRT], eovf[QRT], supp[QRT];
  int  ic[QRT], ec[QRT];

#pragma unroll
  for (int q = 0; q < QRT; ++q) {
    rowq[q] = base + q * BLK + t;
    vq[q]   = rowq[q] < M_ROWS;
    ic[q] = ec[q] = 0;
    ovf[q] = eovf[q] = supp[q] = false;
  }
  if (t == 0) { any254 = 0; }
  if (t < NLVL) lvlcnt[t] = 0;

  // ---- classification: intra-chunk + static-window pred lists ----
#pragma unroll
  for (int q = 0; q < QRT; ++q) {
    if (!vq[q]) continue;
    const int o   = q * BLK + t;
    const int row = rowq[q];
    const int* rp = knn + (long long)row * KNN;
#pragma unroll
    for (int u = 0; u < 16; ++u) {
      int4 d = ((const int4*)rp)[u];
      int js[4] = {d.x, d.y, d.z, d.w};
#pragma unroll
      for (int m = 0; m < 4; ++m) {
        int j = js[m];
        if (j < row) {                            // strict <: ref semantics
          if (j >= base) {
            if (ic[q] < ICAP) il[ic[q]][o] = (unsigned short)(j - base);
            ++ic[q];
          } else if (j >= winb) {
            if (ec[q] < ECAP) exl[ec[q]][o] = (unsigned short)(j - winb);
            ++ec[q];
          }
          // j < winb: covered by the phase-1 reload probe
        }
      }
    }
  }
#pragma unroll
  for (int q = 0; q < QRT; ++q) {
    ovf[q]  = ic[q] > ICAP; if (ovf[q])  ic[q] = ICAP;
    eovf[q] = ec[q] > ECAP; if (eovf[q]) ec[q] = ECAP;
    const int o = q * BLK + t;
    icn[o] = (unsigned char)ic[q];
    unsigned char lv;
    if (!vq[q] || (ic[q] == 0 && !ovf[q])) lv = 0;          // resolves at init
    else if (ovf[q])                       { lv = 254; any254 = 1; }
    else                                   lv = 255;        // level unknown
    lvl[o] = lv;
  }
  __syncthreads();

  // ---- OFF-TURN: topo levels of the intra-chunk DAG (structure-only) ----
  for (int it = 0; it < CHUNK; ++it) {
    bool un = false;
#pragma unroll
    for (int q = 0; q < QRT; ++q) {
      const int o = q * BLK + t;
      if (lvl[o] == 255) {
        bool ready = true, taint = false;
        int  mx = 0;
        for (int x = 0; x < ic[q]; ++x) {
          unsigned char lv = lvl[il[x][o]];
          if (lv == 255) ready = false;
          else if (lv >= 250) taint = true;
          else if ((int)lv > mx) mx = (int)lv;
        }
        if (!ready) un = true;
        else {
          int nl = taint ? 254 : (mx + 1 >= NLVL - 1 ? 254 : mx + 1);
          lvl[o] = (unsigned char)nl;
          if (nl == 254) any254 = 1;              // benign race
        }
      }
    }
    if (__syncthreads_count((int)un) == 0) break;
  }

  // ---- OFF-TURN: counting sort rows into level-ordered worklist ----
#pragma unroll
  for (int q = 0; q < QRT; ++q) {
    const int o = q * BLK + t;
    unsigned char lv = lvl[o];
    if (lv >= 1 && lv < NLVL) atomicAdd(&lvlcnt[lv], 1u);
  }
  __syncthreads();
  if (t == 0) {
    unsigned int off = 0; int lmax = 0;
    for (int L = 1; L < NLVL; ++L) {
      lvloff[L] = off; off += lvlcnt[L];
      if (lvlcnt[L]) lmax = L;
    }
    sh_lmax = lmax;
  }
  __syncthreads();
  if (t >= 1 && t < NLVL) lvlpos[t] = lvloff[t];
  __syncthreads();
#pragma unroll
  for (int q = 0; q < QRT; ++q) {
    const int o = q * BLK + t;
    unsigned char lv = lvl[o];
    if (lv >= 1 && lv < NLVL) {
      unsigned int pos = atomicAdd(&lvlpos[lv], 1u);
      wl[pos] = (unsigned short)o;
    }
  }
  // (no barrier needed until wl is consumed on-turn; phases below barrier anyway)

  int probed_lim = 0;                             // preds j < probed_lim resolved
  int last_pr    = 0;
  int wcop       = 0;

  // ---- phase 1 (b > WCH): forced reload+probe ~WCH steps early ----
  if (b > WCH) {
    if (t < 64) {
      int pr = 0;
      for (int spin = 0; spin < SPINMAX; ++spin) {
        pr = (int)__hip_atomic_load(progress, __ATOMIC_RELAXED,
                                    __HIP_MEMORY_SCOPE_AGENT);
        if (pr >= b - WCH) break;
        __builtin_amdgcn_s_sleep(2);
      }
      if (t == 0) sh_p = (unsigned int)pr;
    }
    __syncthreads();                              // sh_p + wl visible
    int praw1 = (int)sh_p; if (praw1 > b) praw1 = b;
    last_pr = praw1;
    const int wt = praw1 * (CHUNK / 32);
    for (int w = wcop + t; w < wt; w += BLK) lm[w] = bm_load(&bmg[w]);
    wcop = wt;
    __syncthreads();                              // lm visible
    const int lim = praw1 * CHUNK;
#pragma unroll
    for (int q = 0; q < QRT; ++q)
      if (vq[q] && !supp[q])
        supp[q] = probe_reload(knn + (long long)rowq[q] * KNN, lm, 0, lim);
    probed_lim = lim;
  }

  // ---- phase 2: wait for our turn ----
  if (b > 0 && last_pr < b) {
    if (t < 64) {
      for (int spin = 0; spin < SPINMAX; ++spin) {
        int pr = (int)__hip_atomic_load(progress, __ATOMIC_RELAXED,
                                        __HIP_MEMORY_SCOPE_AGENT);
        if (pr >= b) break;
        __builtin_amdgcn_s_sleep(1);
      }
    }
    __syncthreads();                              // turn detected (+ wl visible)
  }

  // ---- on-turn: final mirror + residual window probes ----
  if (b > 0) {
    const int wt = b * (CHUNK / 32);
    for (int w = wcop + t; w < wt; w += BLK) lm[w] = bm_load(&bmg[w]);
    __syncthreads();                              // lm visible
#pragma unroll
    for (int q = 0; q < QRT; ++q) {
      if (!vq[q] || supp[q]) continue;
      const int o = q * BLK + t;
      const int n = ec[q];
      for (int x = 0; x < n; ++x) {
        int j = winb + (int)exl[x][o];
        if (j >= probed_lim && ((lm[j >> 5] >> (j & 31)) & 1u)) { supp[q] = true; break; }
      }
      if (!supp[q] && eovf[q])                    // dropped entries (rare)
        supp[q] = probe_reload(knn + (long long)rowq[q] * KNN, lm, winb, base);
    }
  }

  // ---- init st, then LEVEL-DRIVEN resolve (one pass per level) ----
#pragma unroll
  for (int q = 0; q < QRT; ++q) {
    const int o = q * BLK + t;
    st[o] = (!vq[q] || supp[q]) ? (unsigned char)2
          : ((lvl[o] == 0) ? (unsigned char)1 : (unsigned char)0);
  }
  __syncthreads();

  const int lmax = sh_lmax;
  for (int L = 1; L <= lmax; ++L) {
    const int s0 = (int)lvloff[L];
    const int n  = (int)lvlcnt[L];
    for (int i = t; i < n; i += BLK) {
      const int r = (int)wl[s0 + i];
      if (st[r] != 2) {                           // not externally suppressed
        const int n2 = (int)icn[r];
        bool anyK = false;
        for (int x = 0; x < n2; ++x)
          anyK |= (st[il[x][r]] == 1);            // preds final (levels < L)
        st[r] = anyK ? (unsigned char)2 : (unsigned char)1;
      }
    }
    __syncthreads();
  }

  // ---- catch-all for overflow-tainted rows (P ~ 1e-7): global rescan ----
  if (any254) {
    for (int it = 0; it < CHUNK; ++it) {
      bool un = false;
#pragma unroll
      for (int q = 0; q < QRT; ++q) {
        const int o = q * BLK + t;
        if (lvl[o] == 254 && st[o] == 0) {
          const int row = rowq[q];
          const int* rp = knn + (long long)row * KNN;
          bool anyK = false, allD = true;
#pragma unroll
          for (int k = 0; k < KNN; ++k) {
            int j = rp[k];
            if (j >= base && j < row) {
              unsigned char v = st[j - base];
              anyK |= (v == 1); allD &= (v != 0);
            }
          }
          if (anyK) st[o] = 2; else if (allD) st[o] = 1; else un = true;
        }
      }
      if (__syncthreads_count((int)un) == 0) break;
    }
  }
  __syncthreads();                                // st final for ballots

  // ---- publish: ballots -> LDS -> wave 0 stores + release ----
  bool kq[QRT];
#pragma unroll
  for (int q = 0; q < QRT; ++q)
    kq[q] = vq[q] && (st[q * BLK + t] == 1);

#pragma unroll
  for (int q = 0; q < QRT; ++q) {
    unsigned long long ba = __ballot(kq[q]);      // rows base+q*1024+w*64+lane
    if ((t & 63) == 0) bw[q][t >> 6] = ba;
  }
  __syncthreads();
  if (b < NCH - 1 && t < CHUNK / 64) {            // wave 0: 32 u64 words
    __hip_atomic_store(&bmg64[b * (CHUNK / 64) + t], bw[t >> 4][t & 15],
                       __ATOMIC_RELAXED, __HIP_MEMORY_SCOPE_AGENT);
  }
  if (t == 0)                                     // same wave: stores precede release
    __hip_atomic_store(progress, (unsigned int)(b + 1),
                       __ATOMIC_RELEASE, __HIP_MEMORY_SCOPE_AGENT);

  // ---- outputs (off the chain; block 73's knn overwrites dead bitmask) ----
#pragma unroll
  for (int q = 0; q < QRT; ++q)
    if (vq[q]) out[rowq[q]] = kq[q] ? 1 : 0;

#pragma unroll
  for (int q = 0; q < QRT; ++q) {
    if (!vq[q]) continue;
    const int row = rowq[q];
    const int* rp = knn + (long long)row * KNN;
    int* orow = out + M_ROWS + (long long)row * KNN;
    const bool k = kq[q];
#pragma unroll
    for (int u = 0; u < 16; ++u) {
      int4 d = ((const int4*)rp)[u];
      int4 o4;
      o4.x = k ? d.x : M_ROWS;
      o4.y = k ? d.y : M_ROWS;
      o4.z = k ? d.z : M_ROWS;
      o4.w = k ? d.w : M_ROWS;
      ((int4*)orow)[u] = o4;
    }
  }
}

extern "C" void kernel_launch(void* const* d_in, const int* in_sizes, int n_in,
                              void* d_out, int out_size, void* d_ws, size_t ws_size,
                              hipStream_t stream) {
  const int* knn = (const int*)d_in[1];
  int* out = (int*)d_out;
  unsigned int* progress = (unsigned int*)d_ws;

  init_ws_kernel<<<1, 64, 0, stream>>>(progress);
  nms_chain_kernel<<<NCH, BLK, 0, stream>>>(knn, out, progress);
}

// Round 15
// 677.483 us; speedup vs baseline: 1.0299x; 1.0299x over previous
//
#include <hip/hip_runtime.h>

// Greedy NMS: keep[i] = !any(keep[j] for j in knn[i] if j < i)
//
// Round-15: R12 wait/publish/resolve structure (best per-step: 7.4us) scaled
// to CHUNK=4096 (37 steps). Discriminates fixed-cost vs per-row step models:
// R10's "per-row scaling" datapoint was contaminated (int32 st + 2x sweeps).
//   - ICAP=4 / ECAP=10 + LDS OVERFLOW POOLS: over-cap rows get their full
//     pred list in a shared pool (written off-turn at classification; offsets
//     in owner-thread registers) -> no global loads inside sweep barriers.
//   - all probe loops early-out-free: independent LDS chains pipeline (ILP).
//   - WCH=3: one forced reload (1MB @ ~42GB/s ~ 24us) at pr >= b-3,
//     slack ~27us. On-turn: mirror catch-up + window probes j >= probed_lim.
//   - LDS ~142.5 KB (138 KB proven launchable in R8).
//
// Output encoding (validated round 4): INT32.
//   d_out[0..M)        : kept flags, 1 / 0
//   d_out[M..M+M*64)   : kept_knn, idx or 150000 (tail = bitmask scratch,
//                        owned by block 36 which never publishes)
// d_ws[0..3]: progress counter (zeroed by init kernel each call)

#define M_ROWS 150000
#define KNN    64
#define BLK    1024
#define QRT    4
#define CHUNK  (BLK * QRT)                        // 4096
#define NCH    ((M_ROWS + CHUNK - 1) / CHUNK)     // 37
#define ICAP   4
#define ECAP   10
#define WCH    3                                  // exl window, chunks
#define IPOOL  1024                               // intra overflow pool (shorts)
#define WPOOL  3072                               // window overflow pool (shorts)
#define LMW    (((NCH - 1) * CHUNK) / 32)         // 4608 u32 bitmask words
#define OUT_INTS (M_ROWS + M_ROWS * KNN)
#define BMG_OFF  (OUT_INTS - LMW)
#define SPINMAX  (1 << 22)

__global__ void init_ws_kernel(unsigned int* progress) {
  if (threadIdx.x == 0) *progress = 0u;
}

__device__ __forceinline__ unsigned int bm_load(const unsigned int* p) {
  return __hip_atomic_load(p, __ATOMIC_RELAXED, __HIP_MEMORY_SCOPE_AGENT);
}

// reload a row and probe preds j in [lo, hi) against the LDS bitmask (no early-out)
__device__ __forceinline__ bool probe_reload(const int* __restrict__ rp,
                                             const unsigned int* lm,
                                             int lo, int hi) {
  bool s = false;
#pragma unroll
  for (int u = 0; u < 16; ++u) {
    int4 d = ((const int4*)rp)[u];
    int js[4] = {d.x, d.y, d.z, d.w};
#pragma unroll
    for (int m = 0; m < 4; ++m) {
      int j = js[m];
      if (j >= lo && j < hi && ((lm[j >> 5] >> (j & 31)) & 1u)) s = true;
    }
  }
  return s;
}

__global__ __launch_bounds__(BLK) void nms_chain_kernel(
    const int* __restrict__ knn,
    int* __restrict__ out,
    unsigned int* __restrict__ progress)
{
  const int b    = blockIdx.x;
  const int t    = threadIdx.x;
  const int base = b * CHUNK;
  const int winb = (b > WCH) ? (base - WCH * CHUNK) : 0;   // exl window base

  unsigned int* bmg = (unsigned int*)out + BMG_OFF;
  unsigned long long* bmg64 = (unsigned long long*)bmg;

  __shared__ unsigned char      st[CHUNK];        // 0 unk, 1 kept, 2 supp
  __shared__ unsigned short     il[ICAP][CHUNK];  // transposed intra lists
  __shared__ unsigned short     exl[ECAP][CHUNK]; // transposed window lists
  __shared__ unsigned int       lm[LMW];          // mirrored keep bits
  __shared__ unsigned short     ipool[IPOOL];     // intra overflow pool
  __shared__ unsigned short     wpool[WPOOL];     // window overflow pool
  __shared__ int                ip_top, wp_top;
  __shared__ unsigned long long bw[QRT][BLK / 64];
  __shared__ unsigned int       sh_p;

  int  rowq[QRT];
  bool vq[QRT], iovf[QRT], wovf[QRT], ipbad[QRT], wpbad[QRT], supp[QRT];
  int  ic[QRT], ec[QRT];                          // capped counts
  int  ipo[QRT], ipn[QRT], wpo[QRT], wpn[QRT];    // pool off/cnt

  if (t == 0) { ip_top = 0; wp_top = 0; }
#pragma unroll
  for (int q = 0; q < QRT; ++q) {
    rowq[q] = base + q * BLK + t;
    vq[q]   = rowq[q] < M_ROWS;
    ic[q] = ec[q] = 0;
    iovf[q] = wovf[q] = ipbad[q] = wpbad[q] = supp[q] = false;
    ipo[q] = ipn[q] = wpo[q] = wpn[q] = 0;
  }
  __syncthreads();                                // pool tops initialized

  // ---- classification: intra-chunk + static-window pred lists ----
  int icall[QRT], ecall[QRT];                     // true counts
#pragma unroll
  for (int q = 0; q < QRT; ++q) {
    icall[q] = ecall[q] = 0;
    if (!vq[q]) continue;
    const int o   = q * BLK + t;
    const int row = rowq[q];
    const int* rp = knn + (long long)row * KNN;
#pragma unroll
    for (int u = 0; u < 16; ++u) {
      int4 d = ((const int4*)rp)[u];
      int js[4] = {d.x, d.y, d.z, d.w};
#pragma unroll
      for (int m = 0; m < 4; ++m) {
        int j = js[m];
        if (j < row) {                            // strict <: ref semantics
          if (j >= base) {
            if (icall[q] < ICAP) il[icall[q]][o] = (unsigned short)(j - base);
            ++icall[q];
          } else if (j >= winb) {
            if (ecall[q] < ECAP) exl[ecall[q]][o] = (unsigned short)(j - winb);
            ++ecall[q];
          }
          // j < winb: covered by the phase-1 reload probe
        }
      }
    }
  }
#pragma unroll
  for (int q = 0; q < QRT; ++q) {
    iovf[q] = icall[q] > ICAP; ic[q] = iovf[q] ? ICAP : icall[q];
    wovf[q] = ecall[q] > ECAP; ec[q] = wovf[q] ? ECAP : ecall[q];
  }

  // ---- overflow rows: push FULL pred lists to LDS pools (off-turn, rare) ----
#pragma unroll
  for (int q = 0; q < QRT; ++q) {
    if (!vq[q]) continue;
    const int row = rowq[q];
    const int* rp = knn + (long long)row * KNN;
    if (iovf[q]) {
      int off = atomicAdd(&ip_top, icall[q]);
      if (off + icall[q] <= IPOOL) {
        ipo[q] = off; int k2 = 0;
#pragma unroll
        for (int u = 0; u < 16; ++u) {
          int4 d = ((const int4*)rp)[u];
          int js[4] = {d.x, d.y, d.z, d.w};
#pragma unroll
          for (int m = 0; m < 4; ++m) {
            int j = js[m];
            if (j >= base && j < row) ipool[off + k2++] = (unsigned short)(j - base);
          }
        }
        ipn[q] = k2;
      } else ipbad[q] = true;                     // astronomically rare
    }
    if (wovf[q]) {
      int off = atomicAdd(&wp_top, ecall[q]);
      if (off + ecall[q] <= WPOOL) {
        wpo[q] = off; int k2 = 0;
#pragma unroll
        for (int u = 0; u < 16; ++u) {
          int4 d = ((const int4*)rp)[u];
          int js[4] = {d.x, d.y, d.z, d.w};
#pragma unroll
          for (int m = 0; m < 4; ++m) {
            int j = js[m];
            if (j >= winb && j < base && j < row) wpool[off + k2++] = (unsigned short)(j - winb);
          }
        }
        wpn[q] = k2;
      } else wpbad[q] = true;                     // rare
    }
  }

  int probed_lim = 0;                             // preds j < probed_lim resolved
  int last_pr    = 0;
  int wcop       = 0;

  // ---- phase 1 (b > WCH): forced reload+probe ~WCH steps early ----
  if (b > WCH) {
    if (t < 64) {
      int pr = 0;
      for (int spin = 0; spin < SPINMAX; ++spin) {
        pr = (int)__hip_atomic_load(progress, __ATOMIC_RELAXED,
                                    __HIP_MEMORY_SCOPE_AGENT);
        if (pr >= b - WCH) break;
        __builtin_amdgcn_s_sleep(2);
      }
      if (t == 0) sh_p = (unsigned int)pr;
    }
    __syncthreads();                              // sh_p + pools visible
    int praw1 = (int)sh_p; if (praw1 > b) praw1 = b;
    last_pr = praw1;
    const int wt = praw1 * (CHUNK / 32);
    for (int w = wcop + t; w < wt; w += BLK) lm[w] = bm_load(&bmg[w]);
    wcop = wt;
    __syncthreads();                              // lm visible
    const int lim = praw1 * CHUNK;
#pragma unroll
    for (int q = 0; q < QRT; ++q)
      if (vq[q] && !supp[q])
        supp[q] = probe_reload(knn + (long long)rowq[q] * KNN, lm, 0, lim);
    probed_lim = lim;
  }

  // ---- phase 2: wait for our turn ----
  if (b > 0 && last_pr < b) {
    if (t < 64) {
      for (int spin = 0; spin < SPINMAX; ++spin) {
        int pr = (int)__hip_atomic_load(progress, __ATOMIC_RELAXED,
                                        __HIP_MEMORY_SCOPE_AGENT);
        if (pr >= b) break;
        __builtin_amdgcn_s_sleep(1);
      }
    }
    __syncthreads();                              // turn detected
  }

  // ---- on-turn: final mirror + residual window probes (no early-out) ----
  if (b > 0) {
    const int wt = b * (CHUNK / 32);
    for (int w = wcop + t; w < wt; w += BLK) lm[w] = bm_load(&bmg[w]);
    __syncthreads();                              // lm visible
#pragma unroll
    for (int q = 0; q < QRT; ++q) {
      if (!vq[q] || supp[q]) continue;
      const int o = q * BLK + t;
      bool s = false;
      if (!wovf[q]) {
        const int n = ec[q];
        for (int x = 0; x < n; ++x) {
          int j = winb + (int)exl[x][o];
          s |= (j >= probed_lim) && (((lm[j >> 5] >> (j & 31)) & 1u) != 0u);
        }
      } else if (!wpbad[q]) {
        const int o2 = wpo[q], n2 = wpn[q];
        for (int x = 0; x < n2; ++x) {
          int j = winb + (int)wpool[o2 + x];
          s |= (j >= probed_lim) && (((lm[j >> 5] >> (j & 31)) & 1u) != 0u);
        }
      } else {
        s = probe_reload(knn + (long long)rowq[q] * KNN, lm,
                         probed_lim > winb ? probed_lim : winb, base);
      }
      supp[q] = s;
    }
  }

  // ---- intra-chunk monotone fixed-point (R12 form; pool for ovf rows) ----
#pragma unroll
  for (int q = 0; q < QRT; ++q) {
    const int o = q * BLK + t;
    st[o] = (!vq[q] || supp[q]) ? (unsigned char)2
          : ((icall[q] == 0) ? (unsigned char)1 : (unsigned char)0);
  }
  __syncthreads();

  for (int it = 0; it < CHUNK; ++it) {
    bool un = false;
#pragma unroll
    for (int s = 0; s < 2; ++s) {                 // monotone: stale reads safe
      un = false;
#pragma unroll
      for (int q = 0; q < QRT; ++q) {
        const int o = q * BLK + t;
        if (st[o] == 0) {
          bool anyK = false, allD = true;
          if (!iovf[q]) {
            for (int x = 0; x < ic[q]; ++x) {
              unsigned char v = st[il[x][o]];
              anyK |= (v == 1); allD &= (v != 0);
            }
          } else if (!ipbad[q]) {                 // pool (LDS only)
            const int o2 = ipo[q], n2 = ipn[q];
            for (int x = 0; x < n2; ++x) {
              unsigned char v = st[ipool[o2 + x]];
              anyK |= (v == 1); allD &= (v != 0);
            }
          } else {                                // ultra-rare: global rescan
            const int row = rowq[q];
            const int* rp = knn + (long long)row * KNN;
#pragma unroll
            for (int k = 0; k < KNN; ++k) {
              int j = rp[k];
              if (j >= base && j < row) {
                unsigned char v = st[j - base];
                anyK |= (v == 1); allD &= (v != 0);
              }
            }
          }
          if (anyK) st[o] = 2; else if (allD) st[o] = 1;
          if (st[o] == 0) un = true;
        }
      }
    }
    if (__syncthreads_count((int)un) == 0) break;
  }

  // ---- publish: ballots -> LDS -> wave 0 stores + release ----
  bool kq[QRT];
#pragma unroll
  for (int q = 0; q < QRT; ++q)
    kq[q] = vq[q] && (st[q * BLK + t] == 1);

#pragma unroll
  for (int q = 0; q < QRT; ++q) {
    unsigned long long ba = __ballot(kq[q]);      // rows base+q*1024+w*64+lane
    if ((t & 63) == 0) bw[q][t >> 6] = ba;
  }
  __syncthreads();
  if (b < NCH - 1 && t < CHUNK / 64) {            // wave 0: 64 u64 words
    __hip_atomic_store(&bmg64[b * (CHUNK / 64) + t], bw[t >> 4][t & 15],
                       __ATOMIC_RELAXED, __HIP_MEMORY_SCOPE_AGENT);
  }
  if (t == 0)                                     // same wave: stores precede release
    __hip_atomic_store(progress, (unsigned int)(b + 1),
                       __ATOMIC_RELEASE, __HIP_MEMORY_SCOPE_AGENT);

  // ---- outputs (off the chain; block 36's knn overwrites dead bitmask) ----
#pragma unroll
  for (int q = 0; q < QRT; ++q)
    if (vq[q]) out[rowq[q]] = kq[q] ? 1 : 0;

#pragma unroll
  for (int q = 0; q < QRT; ++q) {
    if (!vq[q]) continue;
    const int row = rowq[q];
    const int* rp = knn + (long long)row * KNN;
    int* orow = out + M_ROWS + (long long)row * KNN;
    const bool k = kq[q];
#pragma unroll
    for (int u = 0; u < 16; ++u) {
      int4 d = ((const int4*)rp)[u];
      int4 o4;
      o4.x = k ? d.x : M_ROWS;
      o4.y = k ? d.y : M_ROWS;
      o4.z = k ? d.z : M_ROWS;
      o4.w = k ? d.w : M_ROWS;
      ((int4*)orow)[u] = o4;
    }
  }
}

extern "C" void kernel_launch(void* const* d_in, const int* in_sizes, int n_in,
                              void* d_out, int out_size, void* d_ws, size_t ws_size,
                              hipStream_t stream) {
  const int* knn = (const int*)d_in[1];
  int* out = (int*)d_out;
  unsigned int* progress = (unsigned int*)d_ws;

  init_ws_kernel<<<1, 64, 0, stream>>>(progress);
  nms_chain_kernel<<<NCH, BLK, 0, stream>>>(knn, out, progress);
}

// Round 16
// 597.785 us; speedup vs baseline: 1.1672x; 1.1333x over previous
//
#include <hip/hip_runtime.h>

// Greedy NMS: keep[i] = !any(keep[j] for j in knn[i] if j < i)
//
// FINAL (= Round-12, the measured optimum: 598us total / 549us chain).
// Session findings baked in:
//   - resident chained-chunk wavefront, 74 x 2048-row chunks; d_ws = 4B
//     progress counter; keep bits ballot-published as a packed bitmask into
//     d_out's tail (last 73 rows' kept_knn slots, overwritten by block 73
//     which never publishes); INT32 output encoding (fingerprinted R3/R4).
//   - chain total ~= M x 3.6ns/row, flat in chunk size (R12 vs R15); per-step
//     cost is head-block on-turn latency, not memory BW (HBM 1.5%, VALU <2%).
//   - one forced full-history reload per block at pr >= b-WCH (~12us, hidden
//     under ~30us slack; single-CU LLC read bw ~42GB/s — R8 finding).
//   - static WCH-chunk window pred lists recorded at classification; on-turn
//     resolution = 64-word mirror + LDS probes only (R9 finding).
//   - wave-0-only polling, 2 block barriers in the wait path (R12's win).
//   - NO per-tick off-turn work (R11 regression), NO precomputed levels
//     (R14 regression), NO on-turn shave micro-opts (R13 neutral).
//
// d_out[0..M)        : kept flags, 1 / 0
// d_out[M..M+M*64)   : kept_knn, idx or 150000 (tail = bitmask scratch)
// d_ws[0..3]: progress counter (zeroed by init kernel each call)

#define M_ROWS 150000
#define KNN    64
#define BLK    1024
#define QRT    2
#define CHUNK  (BLK * QRT)                        // 2048
#define NCH    ((M_ROWS + CHUNK - 1) / CHUNK)     // 74
#define ICAP   6
#define ECAP   12
#define WCH    4                                  // exl window, chunks
#define LMW    (((NCH - 1) * CHUNK) / 32)         // 4672 u32 bitmask words
#define OUT_INTS (M_ROWS + M_ROWS * KNN)
#define BMG_OFF  (OUT_INTS - LMW)

__global__ void init_ws_kernel(unsigned int* progress) {
  if (threadIdx.x == 0) *progress = 0u;
}

__device__ __forceinline__ unsigned int bm_load(const unsigned int* p) {
  return __hip_atomic_load(p, __ATOMIC_RELAXED, __HIP_MEMORY_SCOPE_AGENT);
}

// reload a row and probe preds j in [lo, hi) against the LDS bitmask
__device__ __forceinline__ bool probe_reload(const int* __restrict__ rp,
                                             const unsigned int* lm,
                                             int lo, int hi) {
  bool s = false;
#pragma unroll
  for (int u = 0; u < 16; ++u) {
    int4 d = ((const int4*)rp)[u];
    int js[4] = {d.x, d.y, d.z, d.w};
#pragma unroll
    for (int m = 0; m < 4; ++m) {
      int j = js[m];
      if (j >= lo && j < hi && ((lm[j >> 5] >> (j & 31)) & 1u)) s = true;
    }
  }
  return s;
}

__global__ __launch_bounds__(BLK) void nms_chain_kernel(
    const int* __restrict__ knn,
    int* __restrict__ out,
    unsigned int* __restrict__ progress)
{
  const int b    = blockIdx.x;
  const int t    = threadIdx.x;
  const int base = b * CHUNK;
  const int winb = (b > WCH) ? (base - WCH * CHUNK) : 0;   // exl window base

  unsigned int* bmg = (unsigned int*)out + BMG_OFF;
  unsigned long long* bmg64 = (unsigned long long*)bmg;

  __shared__ unsigned char      st[CHUNK];        // 0 unk, 1 kept, 2 supp
  __shared__ unsigned short     il[ICAP][CHUNK];  // transposed intra lists
  __shared__ unsigned short     exl[ECAP][CHUNK]; // transposed window lists
  __shared__ unsigned int       lm[LMW];          // mirrored keep bits
  __shared__ unsigned long long bw[QRT][BLK / 64];
  __shared__ unsigned int       sh_p;
  __shared__ int                chg;

  int  rowq[QRT];
  bool vq[QRT], ovf[QRT], eovf[QRT], supp[QRT];
  int  ic[QRT], ec[QRT];

#pragma unroll
  for (int q = 0; q < QRT; ++q) {
    rowq[q] = base + q * BLK + t;
    vq[q]   = rowq[q] < M_ROWS;
    ic[q] = ec[q] = 0;
    ovf[q] = eovf[q] = supp[q] = false;
  }

  // ---- classification: intra-chunk + static-window pred lists ----
#pragma unroll
  for (int q = 0; q < QRT; ++q) {
    if (!vq[q]) continue;
    const int o   = q * BLK + t;
    const int row = rowq[q];
    const int* rp = knn + (long long)row * KNN;
#pragma unroll
    for (int u = 0; u < 16; ++u) {
      int4 d = ((const int4*)rp)[u];
      int js[4] = {d.x, d.y, d.z, d.w};
#pragma unroll
      for (int m = 0; m < 4; ++m) {
        int j = js[m];
        if (j < row) {                            // strict <: ref semantics
          if (j >= base) {
            if (ic[q] < ICAP) il[ic[q]][o] = (unsigned short)(j - base);
            ++ic[q];
          } else if (j >= winb) {
            if (ec[q] < ECAP) exl[ec[q]][o] = (unsigned short)(j - winb);
            ++ec[q];
          }
          // j < winb: covered by the phase-1 reload probe
        }
      }
    }
  }
#pragma unroll
  for (int q = 0; q < QRT; ++q) {
    ovf[q]  = ic[q] > ICAP; if (ovf[q])  ic[q] = ICAP;
    eovf[q] = ec[q] > ECAP; if (eovf[q]) ec[q] = ECAP;
  }

  // ---- wait path: wave-0 polling, 2 block barriers total ----
  int praw1 = 0, wcop = 0;
  if (b > WCH) {
    // phase 1: trigger the single forced reload ~WCH steps early
    if (t < 64) {
      int pr = 0;
      for (int spin = 0; spin < (1 << 22); ++spin) {
        pr = (int)__hip_atomic_load(progress, __ATOMIC_RELAXED,
                                    __HIP_MEMORY_SCOPE_AGENT);
        if (pr >= b - WCH) break;
        __builtin_amdgcn_s_sleep(2);
      }
      if (t == 0) sh_p = (unsigned int)pr;
    }
    __syncthreads();                              // barrier 1: sh_p visible
    praw1 = (int)sh_p; if (praw1 > b) praw1 = b;
    const int wt = praw1 * (CHUNK / 32);
    for (int w = t; w < wt; w += BLK) lm[w] = bm_load(&bmg[w]);
    wcop = wt;
    __syncthreads();                              // lm visible
    const int lim = praw1 * CHUNK;
#pragma unroll
    for (int q = 0; q < QRT; ++q)
      if (vq[q] && !supp[q])
        supp[q] = probe_reload(knn + (long long)rowq[q] * KNN, lm, 0, lim);
  }
  if (b > 0 && praw1 < b) {
    // phase 2: wait for our turn (wave 0 spins; others park at the barrier)
    if (t < 64) {
      for (int spin = 0; spin < (1 << 22); ++spin) {
        int pr = (int)__hip_atomic_load(progress, __ATOMIC_RELAXED,
                                        __HIP_MEMORY_SCOPE_AGENT);
        if (pr >= b) break;
        __builtin_amdgcn_s_sleep(1);
      }
    }
    __syncthreads();                              // barrier 2: turn detected
  }
  if (b > 0) {
    const int wt = b * (CHUNK / 32);              // final mirror catch-up
    for (int w = wcop + t; w < wt; w += BLK) lm[w] = bm_load(&bmg[w]);
    __syncthreads();                              // lm visible
    // window probes: only entries >= phase-1 limit are new (older covered)
    const int pr1lim = praw1 * CHUNK;
#pragma unroll
    for (int q = 0; q < QRT; ++q) {
      if (!vq[q] || supp[q]) continue;
      const int o = q * BLK + t;
      const int n = ec[q];
      for (int x = 0; x < n; ++x) {
        int j = winb + (int)exl[x][o];
        if (j >= pr1lim && ((lm[j >> 5] >> (j & 31)) & 1u)) { supp[q] = true; break; }
      }
      if (!supp[q] && eovf[q])                    // dropped entries (rare)
        supp[q] = probe_reload(knn + (long long)rowq[q] * KNN, lm, winb, base);
    }
  }

  // ---- intra-chunk monotone fixed-point (flag-based convergence) ----
#pragma unroll
  for (int q = 0; q < QRT; ++q) {
    const int o = q * BLK + t;
    st[o] = (!vq[q] || supp[q]) ? (unsigned char)2
          : ((ic[q] == 0 && !ovf[q]) ? (unsigned char)1 : (unsigned char)0);
  }
  __syncthreads();

  for (int it = 0; it < CHUNK; ++it) {
    if (t == 0) chg = 0;
    __syncthreads();                              // reset visible
    bool un = false;
#pragma unroll
    for (int s = 0; s < 2; ++s) {                 // monotone: stale reads safe
      un = false;
#pragma unroll
      for (int q = 0; q < QRT; ++q) {
        const int o = q * BLK + t;
        if (st[o] == 0) {
          bool anyK = false, allD = true;
          if (!ovf[q]) {
            for (int x = 0; x < ic[q]; ++x) {
              unsigned char v = st[il[x][o]];
              anyK |= (v == 1); allD &= (v != 0);
            }
          } else {                                // rare: rescan from global
            const int row = rowq[q];
            const int* rp = knn + (long long)row * KNN;
#pragma unroll
            for (int k = 0; k < KNN; ++k) {
              int j = rp[k];
              if (j >= base && j < row) {
                unsigned char v = st[j - base];
                anyK |= (v == 1); allD &= (v != 0);
              }
            }
          }
          if (anyK) st[o] = 2; else if (allD) st[o] = 1;
          if (st[o] == 0) un = true;
        }
      }
    }
    if (un) chg = 1;                              // benign race
    __syncthreads();                              // chg + st visible
    if (chg == 0) break;
  }

  // ---- publish: ballots -> LDS -> wave 0 stores + release ----
  bool kq[QRT];
#pragma unroll
  for (int q = 0; q < QRT; ++q)
    kq[q] = vq[q] && (st[q * BLK + t] == 1);

#pragma unroll
  for (int q = 0; q < QRT; ++q) {
    unsigned long long ba = __ballot(kq[q]);      // rows base+q*1024+w*64+lane
    if ((t & 63) == 0) bw[q][t >> 6] = ba;
  }
  __syncthreads();
  if (b < NCH - 1 && t < CHUNK / 64) {            // wave 0: 32 u64 words
    __hip_atomic_store(&bmg64[b * (CHUNK / 64) + t], bw[t >> 4][t & 15],
                       __ATOMIC_RELAXED, __HIP_MEMORY_SCOPE_AGENT);
  }
  if (t == 0)                                     // same wave: stores precede release
    __hip_atomic_store(progress, (unsigned int)(b + 1),
                       __ATOMIC_RELEASE, __HIP_MEMORY_SCOPE_AGENT);

  // ---- outputs (off the chain; block 73's knn overwrites dead bitmask) ----
#pragma unroll
  for (int q = 0; q < QRT; ++q)
    if (vq[q]) out[rowq[q]] = kq[q] ? 1 : 0;

#pragma unroll
  for (int q = 0; q < QRT; ++q) {
    if (!vq[q]) continue;
    const int row = rowq[q];
    const int* rp = knn + (long long)row * KNN;
    int* orow = out + M_ROWS + (long long)row * KNN;
    const bool k = kq[q];
#pragma unroll
    for (int u = 0; u < 16; ++u) {
      int4 d = ((const int4*)rp)[u];
      int4 o4;
      o4.x = k ? d.x : M_ROWS;
      o4.y = k ? d.y : M_ROWS;
      o4.z = k ? d.z : M_ROWS;
      o4.w = k ? d.w : M_ROWS;
      ((int4*)orow)[u] = o4;
    }
  }
}

extern "C" void kernel_launch(void* const* d_in, const int* in_sizes, int n_in,
                              void* d_out, int out_size, void* d_ws, size_t ws_size,
                              hipStream_t stream) {
  const int* knn = (const int*)d_in[1];
  int* out = (int*)d_out;
  unsigned int* progress = (unsigned int*)d_ws;

  init_ws_kernel<<<1, 64, 0, stream>>>(progress);
  nms_chain_kernel<<<NCH, BLK, 0, stream>>>(knn, out, progress);
}